// Round 1
// baseline (550.388 us; speedup 1.0000x reference)
//
#include <hip/hip_runtime.h>
#include <math.h>

#define N_NODES 100000
#define N_EDGES 3200000
#define F_IN    128
#define HID     16
#define NGRAPH  64

// Workspace layout (units of 4-byte elements, 16B-aligned region starts)
#define OFF_CNT    0         // [N] int      edge counts per dst (deg-1)
#define OFF_CURSOR 100000    // [N] int      fill cursors
#define OFF_DIS    200000    // [N] f32      rsqrt(deg)
#define OFF_ROW    300000    // [N+1] int    CSR row starts
#define OFF_BSUM   400016    // [64] int     scan block sums
#define OFF_COL    400080    // [E] int      CSR col (src) indices
#define OFF_BUFA   3600080   // [N*16] f32
#define OFF_BUFB   5200080   // [N*16] f32
// total 6,800,080 elems = ~27.2 MB

__global__ void count_k(const int* __restrict__ ei, int* __restrict__ cnt) {
    int e = blockIdx.x * blockDim.x + threadIdx.x;
    if (e < N_EDGES) atomicAdd(&cnt[ei[N_EDGES + e]], 1);
}

__global__ void dis_k(const int* __restrict__ cnt, float* __restrict__ dis) {
    int i = blockIdx.x * blockDim.x + threadIdx.x;
    if (i < N_NODES) dis[i] = rsqrtf((float)cnt[i] + 1.0f);
}

// ---- 3-kernel exclusive scan of cnt[N] -> row_start[N] (+ bsum totals) ----
__global__ void scan1_k(const int* __restrict__ cnt, int* __restrict__ out,
                        int* __restrict__ bsum) {
    __shared__ int warpSums[4];
    int base = blockIdx.x * 2048 + threadIdx.x * 8;
    int v[8];
    int s = 0;
#pragma unroll
    for (int t = 0; t < 8; ++t) {
        int i = base + t;
        v[t] = (i < N_NODES) ? cnt[i] : 0;
        s += v[t];
    }
    int lane = threadIdx.x & 63, wid = threadIdx.x >> 6;
    int sc = s;
#pragma unroll
    for (int d = 1; d < 64; d <<= 1) {
        int o = __shfl_up(sc, d);
        if (lane >= d) sc += o;
    }
    if (lane == 63) warpSums[wid] = sc;
    __syncthreads();
    int wOff = 0;
    for (int w = 0; w < wid; ++w) wOff += warpSums[w];
    int excl = wOff + sc - s;
#pragma unroll
    for (int t = 0; t < 8; ++t) {
        int i = base + t;
        if (i < N_NODES) out[i] = excl;
        excl += v[t];
    }
    if (threadIdx.x == 255) bsum[blockIdx.x] = wOff + sc;
}

__global__ void scan2_k(int* __restrict__ bsum, int nb) {
    int lane = threadIdx.x;
    int v = (lane < nb) ? bsum[lane] : 0;
    int sc = v;
#pragma unroll
    for (int d = 1; d < 64; d <<= 1) {
        int o = __shfl_up(sc, d);
        if (lane >= d) sc += o;
    }
    if (lane < nb) bsum[lane] = sc - v;  // exclusive
}

__global__ void scan3_k(int* __restrict__ row_start, const int* __restrict__ bsum) {
    int i = blockIdx.x * blockDim.x + threadIdx.x;
    if (i < N_NODES) row_start[i] += bsum[i >> 11];
    if (i == 0) row_start[N_NODES] = N_EDGES;
}

__global__ void fill_k(const int* __restrict__ ei, const int* __restrict__ row_start,
                       int* __restrict__ cursor, int* __restrict__ col) {
    int e = blockIdx.x * blockDim.x + threadIdx.x;
    if (e < N_EDGES) {
        int s = ei[e];
        int d = ei[N_EDGES + e];
        int pos = atomicAdd(&cursor[d], 1);
        col[row_start[d] + pos] = s;
    }
}

// ---- h = x @ W1   (x: [N,128], W1: [128,16]) ----
__global__ void transform1_k(const float* __restrict__ x, const float* __restrict__ W,
                             float* __restrict__ out) {
    int i = blockIdx.x * blockDim.x + threadIdx.x;
    if (i >= N_NODES) return;
    const float4* xr = (const float4*)(x + (size_t)i * F_IN);
    float acc[16];
#pragma unroll
    for (int j = 0; j < 16; ++j) acc[j] = 0.f;
#pragma unroll 4
    for (int k4 = 0; k4 < F_IN / 4; ++k4) {
        float4 xv = xr[k4];
        const float* xs = &xv.x;
#pragma unroll
        for (int kk = 0; kk < 4; ++kk) {
            int k = k4 * 4 + kk;
            float xk = xs[kk];
#pragma unroll
            for (int j = 0; j < 16; ++j)
                acc[j] = fmaf(xk, W[k * 16 + j], acc[j]);  // W idx uniform -> s_load
        }
    }
    float4* o = (float4*)(out + (size_t)i * 16);
#pragma unroll
    for (int q = 0; q < 4; ++q)
        o[q] = make_float4(acc[q * 4], acc[q * 4 + 1], acc[q * 4 + 2], acc[q * 4 + 3]);
}

// ---- h = hin @ W2  (hin: [N,16], W2: [16,16]) ----
__global__ void transform2_k(const float* __restrict__ h, const float* __restrict__ W,
                             float* __restrict__ out) {
    int i = blockIdx.x * blockDim.x + threadIdx.x;
    if (i >= N_NODES) return;
    const float4* hr = (const float4*)(h + (size_t)i * 16);
    float hv[16];
#pragma unroll
    for (int q = 0; q < 4; ++q) {
        float4 t = hr[q];
        hv[q * 4 + 0] = t.x; hv[q * 4 + 1] = t.y; hv[q * 4 + 2] = t.z; hv[q * 4 + 3] = t.w;
    }
    float acc[16];
#pragma unroll
    for (int j = 0; j < 16; ++j) acc[j] = 0.f;
#pragma unroll
    for (int k = 0; k < 16; ++k) {
#pragma unroll
        for (int j = 0; j < 16; ++j)
            acc[j] = fmaf(hv[k], W[k * 16 + j], acc[j]);
    }
    float4* o = (float4*)(out + (size_t)i * 16);
#pragma unroll
    for (int q = 0; q < 4; ++q)
        o[q] = make_float4(acc[q * 4], acc[q * 4 + 1], acc[q * 4 + 2], acc[q * 4 + 3]);
}

// ---- propagate: hout[i] = relu(dis[i]*sum_e dis[src]*hin[src] + dis[i]^2*hin[i] + b)
__global__ void propagate_k(const float* __restrict__ hin, const float* __restrict__ dis,
                            const int* __restrict__ row_start, const int* __restrict__ col,
                            const float* __restrict__ bias, float* __restrict__ hout) {
    int gid = blockIdx.x * blockDim.x + threadIdx.x;
    int node = gid >> 4;
    int j = gid & 15;
    if (node >= N_NODES) return;
    int e0 = row_start[node];
    int e1 = row_start[node + 1];
    float acc = 0.f;
    for (int e = e0; e < e1; ++e) {
        int s = col[e];
        acc = fmaf(dis[s], hin[s * 16 + j], acc);
    }
    float di = dis[node];
    float v = fmaf(di, acc, fmaf(di * di, hin[node * 16 + j], bias[j]));
    hout[node * 16 + j] = fmaxf(v, 0.f);
}

// ---- pool per graph (batch sorted) + sigmoid(pooled @ fc_w + fc_b) ----
__global__ void pool_k(const float* __restrict__ h2, const int* __restrict__ batch,
                       const float* __restrict__ fcw, const float* __restrict__ fcb,
                       float* __restrict__ out) {
    __shared__ float partial[16][16];
    int g = blockIdx.x;
    int lane16 = threadIdx.x & 15, grp = threadIdx.x >> 4;
    // lower_bound(batch, g) and lower_bound(batch, g+1)
    int lo = 0, hi = N_NODES;
    while (lo < hi) { int m = (lo + hi) >> 1; if (batch[m] < g) lo = m + 1; else hi = m; }
    int start = lo;
    lo = start; hi = N_NODES;
    while (lo < hi) { int m = (lo + hi) >> 1; if (batch[m] < g + 1) lo = m + 1; else hi = m; }
    int end = lo;
    float acc = 0.f;
    for (int i = start + grp; i < end; i += 16) acc += h2[i * 16 + lane16];
    partial[grp][lane16] = acc;
    __syncthreads();
    if (threadIdx.x < 16) {
        float s = 0.f;
#pragma unroll
        for (int gg = 0; gg < 16; ++gg) s += partial[gg][threadIdx.x];
        partial[0][threadIdx.x] = s * fcw[threadIdx.x];
    }
    __syncthreads();
    if (threadIdx.x == 0) {
        float z = fcb[0];
#pragma unroll
        for (int j = 0; j < 16; ++j) z += partial[0][j];
        out[g] = 1.0f / (1.0f + expf(-z));
    }
}

extern "C" void kernel_launch(void* const* d_in, const int* in_sizes, int n_in,
                              void* d_out, int out_size, void* d_ws, size_t ws_size,
                              hipStream_t stream) {
    const float* x    = (const float*)d_in[0];
    const int*   ei   = (const int*)d_in[1];
    const int*   batch= (const int*)d_in[2];
    const float* W1   = (const float*)d_in[3];
    const float* b1   = (const float*)d_in[4];
    const float* W2   = (const float*)d_in[5];
    const float* b2   = (const float*)d_in[6];
    const float* fcw  = (const float*)d_in[7];
    const float* fcb  = (const float*)d_in[8];
    float* out = (float*)d_out;

    float* ws = (float*)d_ws;
    int*   cnt      = (int*)(ws + OFF_CNT);
    int*   cursor   = (int*)(ws + OFF_CURSOR);
    float* dis      = ws + OFF_DIS;
    int*   row_start= (int*)(ws + OFF_ROW);
    int*   bsum     = (int*)(ws + OFF_BSUM);
    int*   col      = (int*)(ws + OFF_COL);
    float* bufA     = ws + OFF_BUFA;
    float* bufB     = ws + OFF_BUFB;

    // zero cnt + cursor (adjacent)
    hipMemsetAsync(cnt, 0, (size_t)2 * N_NODES * sizeof(int), stream);

    const int B = 256;
    int gE = (N_EDGES + B - 1) / B;     // 12500
    int gN = (N_NODES + B - 1) / B;     // 391
    int gNH = (N_NODES * 16 + B - 1) / B; // 6250
    int nbScan = (N_NODES + 2047) / 2048; // 49

    count_k<<<gE, B, 0, stream>>>(ei, cnt);
    dis_k<<<gN, B, 0, stream>>>(cnt, dis);
    scan1_k<<<nbScan, B, 0, stream>>>(cnt, row_start, bsum);
    scan2_k<<<1, 64, 0, stream>>>(bsum, nbScan);
    scan3_k<<<gN, B, 0, stream>>>(row_start, bsum);
    fill_k<<<gE, B, 0, stream>>>(ei, row_start, cursor, col);

    transform1_k<<<gN, B, 0, stream>>>(x, W1, bufA);
    propagate_k<<<gNH, B, 0, stream>>>(bufA, dis, row_start, col, b1, bufB);
    transform2_k<<<gN, B, 0, stream>>>(bufB, W2, bufA);
    propagate_k<<<gNH, B, 0, stream>>>(bufA, dis, row_start, col, b2, bufB);
    pool_k<<<NGRAPH, B, 0, stream>>>(bufB, batch, fcw, fcb, out);
}